// Round 4
// baseline (632.037 us; speedup 1.0000x reference)
//
#include <hip/hip_runtime.h>
#include <hip/hip_bf16.h>
#include <math.h>

#define B_ROWS 65536
#define D_DIM 256
#define C_DIM 128
#define H_DIM 1024

typedef __bf16 bf16x8 __attribute__((ext_vector_type(8)));
typedef float f32x4 __attribute__((ext_vector_type(4)));
typedef short short8 __attribute__((ext_vector_type(8)));

__device__ __forceinline__ unsigned short f2bf(float f) {
    unsigned int u = __float_as_uint(f);
    u += 0x7fffu + ((u >> 16) & 1u);
    return (unsigned short)(u >> 16);
}

__device__ __forceinline__ void gl2lds16(const void* g, void* l) {
    __builtin_amdgcn_global_load_lds(
        (const __attribute__((address_space(1))) unsigned int*)g,
        (__attribute__((address_space(3))) unsigned int*)l, 16, 0, 0);
}

__device__ __forceinline__ void swizzle_mn(int id, int mtiles, int& m, int& n) {
    if ((mtiles & 7) == 0) {
        int g = id >> 6, r = id & 63;
        m = g * 8 + (r & 7);
        n = r >> 3;
    } else {
        m = id >> 3;
        n = id & 7;
    }
}

// dst[n*R + k] = bf16(src[k*C + n]); src is R x C row-major, dst N x K
__global__ void transpose_bf16(const float* __restrict__ src, short* __restrict__ dst,
                               int R, int C, int total) {
    int tid = blockIdx.x * 256 + threadIdx.x;
    if (tid >= total) return;
    int per = R >> 3;
    int n = tid / per;
    int k0 = (tid - n * per) << 3;
    short8 o;
#pragma unroll
    for (int j = 0; j < 8; ++j) o[j] = (short)f2bf(src[(size_t)(k0 + j) * C + n]);
    *(short8*)&dst[(size_t)n * R + k0] = o;
}

__global__ void prep_b3(const float* __restrict__ bs, const float* __restrict__ bt,
                        float* __restrict__ b3) {
    int i = threadIdx.x;
    b3[i] = (i < 128) ? bs[i] : bt[i - 128];
}

// GEMM1 fused: A[m][k] = k<128 ? x[m][2k] : cond[m][k-128], B = W1T (1024 x 256).
// H1 = relu(A@W1 + b1) bf16.
__global__ __launch_bounds__(256) void gemm1_fused(
    const float* __restrict__ x, const float* __restrict__ cond,
    const short* __restrict__ Bw, const float* __restrict__ bias,
    unsigned short* __restrict__ H1, int mtiles) {
    constexpr int BK = 64, K = 256, N = 1024;
    __shared__ __align__(16) short As[128 * BK];
    __shared__ __align__(16) short Bs[128 * BK];
    const int tid = threadIdx.x;
    const int lane = tid & 63;
    const int wave = tid >> 6;
    int mt, nt;
    swizzle_mn(blockIdx.x, mtiles, mt, nt);
    const int tm = mt * 128, tn = nt * 128;
    const int mo = (wave >> 1) * 64;
    const int no = (wave & 1) * 64;

    f32x4 acc[4][4];
#pragma unroll
    for (int i = 0; i < 4; ++i)
#pragma unroll
        for (int j = 0; j < 4; ++j) acc[i][j] = f32x4{0.f, 0.f, 0.f, 0.f};

    const int srow = lane >> 3;
    const int skb = (lane & 7) ^ srow;

#pragma unroll
    for (int kc = 0; kc < K; kc += BK) {
        __syncthreads();
#pragma unroll
        for (int i = 0; i < 4; ++i) {
            int c = wave * 4 + i;
            int row = c * 8 + srow;
            int kcol = kc + skb * 8;
            float v[8];
            if (kc < 128) {
                const float4* p = (const float4*)(x + (size_t)(tm + row) * 256 + 2 * kcol);
                float4 a = p[0], b = p[1], cc = p[2], d = p[3];
                v[0]=a.x; v[1]=a.z; v[2]=b.x; v[3]=b.z; v[4]=cc.x; v[5]=cc.z; v[6]=d.x; v[7]=d.z;
            } else {
                const float4* p = (const float4*)(cond + (size_t)(tm + row) * 128 + (kcol - 128));
                float4 a = p[0], b = p[1];
                v[0]=a.x; v[1]=a.y; v[2]=a.z; v[3]=a.w; v[4]=b.x; v[5]=b.y; v[6]=b.z; v[7]=b.w;
            }
            short8 o;
#pragma unroll
            for (int j = 0; j < 8; ++j) o[j] = (short)f2bf(v[j]);
            *(short8*)&As[c * 512 + lane * 8] = o;
            gl2lds16(Bw + (size_t)(tn + row) * K + kc + skb * 8, &Bs[c * 512]);
        }
        __syncthreads();
#pragma unroll
        for (int kk = 0; kk < 2; ++kk) {
            bf16x8 af[4], bfr[4];
            int kb = kk * 4 + (lane >> 4);
#pragma unroll
            for (int t = 0; t < 4; ++t) {
                int r = mo + t * 16 + (lane & 15);
                af[t] = *(const bf16x8*)&As[r * BK + ((kb ^ (r & 7)) << 3)];
                int n = no + t * 16 + (lane & 15);
                bfr[t] = *(const bf16x8*)&Bs[n * BK + ((kb ^ (n & 7)) << 3)];
            }
#pragma unroll
            for (int i = 0; i < 4; ++i)
#pragma unroll
                for (int j = 0; j < 4; ++j)
                    acc[i][j] = __builtin_amdgcn_mfma_f32_16x16x32_bf16(
                        af[i], bfr[j], acc[i][j], 0, 0, 0);
        }
    }

#pragma unroll
    for (int j = 0; j < 4; ++j) {
        int col = tn + no + j * 16 + (lane & 15);
        float bb = bias[col];
#pragma unroll
        for (int i = 0; i < 4; ++i) {
            int row0 = tm + mo + i * 16 + ((lane >> 4) << 2);
            f32x4 v = acc[i][j];
#pragma unroll
            for (int rr = 0; rr < 4; ++rr)
                H1[(size_t)(row0 + rr) * N + col] = f2bf(fmaxf(v[rr] + bb, 0.f));
        }
    }
}

// Fused GEMM2+GEMM3+finalize. Block = 64 rows, 4 waves (256 thr).
// For nc in 0..7: H2chunk(64x128) = relu(H1 @ W2T[nc*128..][.] + b2) -> LDS ping,
// then P(64x256, in regs) += H2chunk @ W3T[:, nc*128..]. Epilogue: tanh/exp/affine.
__global__ __launch_bounds__(256, 2) void gemm23_fused(
    const short* __restrict__ H1, const short* __restrict__ W2T,
    const float* __restrict__ b2, const short* __restrict__ W3T,
    const float* __restrict__ b3, const float* __restrict__ x,
    float* __restrict__ out, float* __restrict__ logdet) {
    constexpr int K2 = 1024;
    // As 64x64 (8KB) | Ws2 128x64 (16KB) | ping 64x136 bf16 (17KB). Tbuf overlays.
    __shared__ __align__(16) char raw[8192 + 16384 + 17408];
    __shared__ float rowsum[64];
    short* As = (short*)raw;
    short* Ws2 = (short*)(raw + 8192);
    short* ping = (short*)(raw + 24576);
    float* Tbuf = (float*)raw;            // 64 x 132 f32 = 33792 B
    const int tid = threadIdx.x;
    const int lane = tid & 63;
    const int wave = tid >> 6;
    const int tm = blockIdx.x * 64;
    const int srow = lane >> 3;
    const int skb = (lane & 7) ^ srow;
    const int l15 = lane & 15;
    const int quad = lane >> 4;

    if (tid < 64) rowsum[tid] = 0.f;

    f32x4 acc3[4][4];
#pragma unroll
    for (int i = 0; i < 4; ++i)
#pragma unroll
        for (int j = 0; j < 4; ++j) acc3[i][j] = f32x4{0.f, 0.f, 0.f, 0.f};

#pragma unroll 1
    for (int nc = 0; nc < 8; ++nc) {
        f32x4 acc2[4][2];
#pragma unroll
        for (int i = 0; i < 4; ++i)
#pragma unroll
            for (int j = 0; j < 2; ++j) acc2[i][j] = f32x4{0.f, 0.f, 0.f, 0.f};

        for (int kc = 0; kc < K2; kc += 64) {
            __syncthreads();
#pragma unroll
            for (int i = 0; i < 6; ++i) {       // 24 chunks: 8 A + 16 W2
                int c = wave * 6 + i;
                if (c < 8) {
                    int row = c * 8 + srow;
                    gl2lds16(H1 + (size_t)(tm + row) * K2 + kc + skb * 8, &As[c * 512]);
                } else {
                    int c2 = c - 8;
                    int row = c2 * 8 + srow;
                    gl2lds16(W2T + (size_t)(nc * 128 + row) * K2 + kc + skb * 8,
                             &Ws2[c2 * 512]);
                }
            }
            __syncthreads();
#pragma unroll
            for (int kk = 0; kk < 2; ++kk) {
                int kb = kk * 4 + quad;
                bf16x8 af[4], bfr[2];
#pragma unroll
                for (int mt = 0; mt < 4; ++mt) {
                    int r = mt * 16 + l15;
                    af[mt] = *(const bf16x8*)&As[r * 64 + ((kb ^ (r & 7)) << 3)];
                }
#pragma unroll
                for (int nt = 0; nt < 2; ++nt) {
                    int n = wave * 32 + nt * 16 + l15;
                    bfr[nt] = *(const bf16x8*)&Ws2[n * 64 + ((kb ^ (n & 7)) << 3)];
                }
#pragma unroll
                for (int mt = 0; mt < 4; ++mt)
#pragma unroll
                    for (int nt = 0; nt < 2; ++nt)
                        acc2[mt][nt] = __builtin_amdgcn_mfma_f32_16x16x32_bf16(
                            af[mt], bfr[nt], acc2[mt][nt], 0, 0, 0);
            }
        }
        // H2 chunk epilogue: relu+bias -> bf16 ping (ping reads from prev nc are
        // long done: 16 barriered k-iters since).
        __syncthreads();
#pragma unroll
        for (int nt = 0; nt < 2; ++nt) {
            int col = wave * 32 + nt * 16 + l15;
            float bb = b2[nc * 128 + col];
#pragma unroll
            for (int mt = 0; mt < 4; ++mt) {
#pragma unroll
                for (int rr = 0; rr < 4; ++rr) {
                    int m = mt * 16 + quad * 4 + rr;
                    ping[m * 136 + col] = (short)f2bf(fmaxf(acc2[mt][nt][rr] + bb, 0.f));
                }
            }
        }
        __syncthreads();
        // GEMM3 partial: P += ping(64x128) @ W3T[:, nc*128 .. +128]
#pragma unroll
        for (int ks = 0; ks < 4; ++ks) {
            bf16x8 af[4], bfr2[4];
#pragma unroll
            for (int mt = 0; mt < 4; ++mt) {
                int m = mt * 16 + l15;
                af[mt] = *(const bf16x8*)&ping[m * 136 + ks * 32 + quad * 8];
            }
#pragma unroll
            for (int nt = 0; nt < 4; ++nt) {
                int n = wave * 64 + nt * 16 + l15;
                bfr2[nt] = *(const bf16x8*)&W3T[(size_t)n * 1024 + nc * 128 + ks * 32 + quad * 8];
            }
#pragma unroll
            for (int mt = 0; mt < 4; ++mt)
#pragma unroll
                for (int nt = 0; nt < 4; ++nt)
                    acc3[mt][nt] = __builtin_amdgcn_mfma_f32_16x16x32_bf16(
                        af[mt], bfr2[nt], acc3[mt][nt], 0, 0, 0);
        }
    }

    // Finalize. P cols 0..127 = ls_pre (waves 0,1), 128..255 = t (waves 2,3).
    __syncthreads();
    if (wave >= 2) {
#pragma unroll
        for (int nt = 0; nt < 4; ++nt) {
            int col = wave * 64 + nt * 16 + l15;   // 128..255
            float bb = b3[col];
            int cl = col - 128;
#pragma unroll
            for (int mt = 0; mt < 4; ++mt) {
#pragma unroll
                for (int rr = 0; rr < 4; ++rr) {
                    int m = mt * 16 + quad * 4 + rr;
                    Tbuf[m * 132 + cl] = acc3[mt][nt][rr] + bb;
                }
            }
        }
    }
    __syncthreads();
    if (wave < 2) {
#pragma unroll
        for (int mt = 0; mt < 4; ++mt) {
#pragma unroll
            for (int rr = 0; rr < 4; ++rr) {
                int m = mt * 16 + quad * 4 + rr;
                int grow = tm + m;
                float s = 0.f;
#pragma unroll
                for (int nt = 0; nt < 4; ++nt) {
                    int j = wave * 64 + nt * 16 + l15;   // 0..127
                    float ls = tanhf(acc3[mt][nt][rr] + b3[j]);
                    s += ls;
                    float tt = Tbuf[m * 132 + j];
                    float2 xv = *(const float2*)&x[(size_t)grow * 256 + 2 * j];
                    float2 ov;
                    ov.x = xv.x;
                    ov.y = xv.y * expf(ls) + tt;
                    *(float2*)&out[(size_t)grow * 256 + 2 * j] = ov;
                }
                s += __shfl_xor(s, 1);
                s += __shfl_xor(s, 2);
                s += __shfl_xor(s, 4);
                s += __shfl_xor(s, 8);
                if (l15 == 0) atomicAdd(&rowsum[m], s);
            }
        }
    }
    __syncthreads();
    if (tid < 64) logdet[tm + tid] = rowsum[tid];
}

extern "C" void kernel_launch(void* const* d_in, const int* in_sizes, int n_in,
                              void* d_out, int out_size, void* d_ws, size_t ws_size,
                              hipStream_t stream) {
    const float* x = (const float*)d_in[0];
    const float* cond = (const float*)d_in[1];
    const float* W1 = (const float*)d_in[2];
    const float* b1 = (const float*)d_in[3];
    const float* W2 = (const float*)d_in[4];
    const float* b2 = (const float*)d_in[5];
    const float* Wsp = (const float*)d_in[6];
    const float* bs = (const float*)d_in[7];
    const float* Wtp = (const float*)d_in[8];
    const float* bt = (const float*)d_in[9];

    char* ws = (char*)d_ws;
    short* W1T = (short*)(ws);                          // 1024x256 bf16 = 512 KB
    short* W2T = (short*)(ws + 524288ull);              // 1024x1024 bf16 = 2 MB
    short* W3T = (short*)(ws + 2621440ull);             // 256x1024 bf16 = 512 KB
    float* b3  = (float*)(ws + 3145728ull);             // 1 KB
    const size_t chunk_base = 3149824ull;

    // Per-chunk scratch: H1 only = 2048 B/row.
    int n_chunks = 1;
    while (n_chunks < 512) {
        size_t rp = (size_t)B_ROWS / n_chunks;
        if (chunk_base + rp * 2048ull <= ws_size) break;
        n_chunks *= 2;
    }
    const size_t RP = (size_t)B_ROWS / n_chunks;

    float* out = (float*)d_out;
    float* logdet = out + (size_t)B_ROWS * D_DIM;

    transpose_bf16<<<(32768 + 255) / 256, 256, 0, stream>>>(W1, W1T, 256, 1024, 32768);
    transpose_bf16<<<(131072 + 255) / 256, 256, 0, stream>>>(W2, W2T, 1024, 1024, 131072);
    transpose_bf16<<<(16384 + 255) / 256, 256, 0, stream>>>(Wsp, W3T, 1024, 128, 16384);
    transpose_bf16<<<(16384 + 255) / 256, 256, 0, stream>>>(Wtp, W3T + 131072, 1024, 128, 16384);
    prep_b3<<<1, 256, 0, stream>>>(bs, bt, b3);

    for (int c = 0; c < n_chunks; ++c) {
        const size_t r0 = (size_t)c * RP;
        short* H1 = (short*)(ws + chunk_base);
        const int mtiles = (int)(RP / 128);

        gemm1_fused<<<mtiles * 8, 256, 0, stream>>>(
            x + r0 * D_DIM, cond + r0 * C_DIM, W1T, b1, (unsigned short*)H1, mtiles);
        gemm23_fused<<<(int)(RP / 64), 256, 0, stream>>>(
            H1, W2T, b2, W3T, b3, x + r0 * D_DIM, out + r0 * D_DIM, logdet + r0);
    }
}

// Round 5
// 509.048 us; speedup vs baseline: 1.2416x; 1.2416x over previous
//
#include <hip/hip_runtime.h>
#include <hip/hip_bf16.h>
#include <math.h>

#define B_ROWS 65536
#define D_DIM 256
#define C_DIM 128
#define H_DIM 1024

typedef __bf16 bf16x8 __attribute__((ext_vector_type(8)));
typedef float f32x4 __attribute__((ext_vector_type(4)));
typedef short short8 __attribute__((ext_vector_type(8)));

__device__ __forceinline__ unsigned short f2bf(float f) {
    unsigned int u = __float_as_uint(f);
    u += 0x7fffu + ((u >> 16) & 1u);
    return (unsigned short)(u >> 16);
}

__device__ __forceinline__ void gl2lds16(const void* g, void* l) {
    __builtin_amdgcn_global_load_lds(
        (const __attribute__((address_space(1))) unsigned int*)g,
        (__attribute__((address_space(3))) unsigned int*)l, 16, 0, 0);
}

// XCD-aware swizzle: all 8 N-tiles of one M-tile land on the same XCD.
__device__ __forceinline__ void swizzle_mn(int id, int mtiles, int& m, int& n) {
    if ((mtiles & 7) == 0) {
        int g = id >> 6, r = id & 63;
        m = g * 8 + (r & 7);
        n = r >> 3;
    } else {
        m = id >> 3;
        n = id & 7;
    }
}

// dst[n*R + k] = bf16(src[k*C + n]); src is R x C row-major, dst N x K
__global__ void transpose_bf16(const float* __restrict__ src, short* __restrict__ dst,
                               int R, int C, int total) {
    int tid = blockIdx.x * 256 + threadIdx.x;
    if (tid >= total) return;
    int per = R >> 3;
    int n = tid / per;
    int k0 = (tid - n * per) << 3;
    short8 o;
#pragma unroll
    for (int j = 0; j < 8; ++j) o[j] = (short)f2bf(src[(size_t)(k0 + j) * C + n]);
    *(short8*)&dst[(size_t)n * R + k0] = o;
}

__global__ void prep_b3(const float* __restrict__ bs, const float* __restrict__ bt,
                        float* __restrict__ b3) {
    int i = threadIdx.x;
    b3[i] = (i < 128) ? bs[i] : bt[i - 128];
}

// GEMM1 fused: A[m][k] = k<128 ? x[m][2k] : cond[m][k-128], B = W1T (1024 x 256).
// H1 = relu(A@W1 + b1) bf16.
__global__ __launch_bounds__(256) void gemm1_fused(
    const float* __restrict__ x, const float* __restrict__ cond,
    const short* __restrict__ Bw, const float* __restrict__ bias,
    unsigned short* __restrict__ H1, int mtiles) {
    constexpr int BK = 64, K = 256, N = 1024;
    __shared__ __align__(16) short As[128 * BK];
    __shared__ __align__(16) short Bs[128 * BK];
    const int tid = threadIdx.x;
    const int lane = tid & 63;
    const int wave = tid >> 6;
    int mt, nt;
    swizzle_mn(blockIdx.x, mtiles, mt, nt);
    const int tm = mt * 128, tn = nt * 128;
    const int mo = (wave >> 1) * 64;
    const int no = (wave & 1) * 64;

    f32x4 acc[4][4];
#pragma unroll
    for (int i = 0; i < 4; ++i)
#pragma unroll
        for (int j = 0; j < 4; ++j) acc[i][j] = f32x4{0.f, 0.f, 0.f, 0.f};

    const int srow = lane >> 3;
    const int skb = (lane & 7) ^ srow;

#pragma unroll
    for (int kc = 0; kc < K; kc += BK) {
        __syncthreads();
#pragma unroll
        for (int i = 0; i < 4; ++i) {
            int c = wave * 4 + i;
            int row = c * 8 + srow;
            int kcol = kc + skb * 8;
            float v[8];
            if (kc < 128) {
                const float4* p = (const float4*)(x + (size_t)(tm + row) * 256 + 2 * kcol);
                float4 a = p[0], b = p[1], cc = p[2], d = p[3];
                v[0]=a.x; v[1]=a.z; v[2]=b.x; v[3]=b.z; v[4]=cc.x; v[5]=cc.z; v[6]=d.x; v[7]=d.z;
            } else {
                const float4* p = (const float4*)(cond + (size_t)(tm + row) * 128 + (kcol - 128));
                float4 a = p[0], b = p[1];
                v[0]=a.x; v[1]=a.y; v[2]=a.z; v[3]=a.w; v[4]=b.x; v[5]=b.y; v[6]=b.z; v[7]=b.w;
            }
            short8 o;
#pragma unroll
            for (int j = 0; j < 8; ++j) o[j] = (short)f2bf(v[j]);
            *(short8*)&As[c * 512 + lane * 8] = o;
            gl2lds16(Bw + (size_t)(tn + row) * K + kc + skb * 8, &Bs[c * 512]);
        }
        __syncthreads();
#pragma unroll
        for (int kk = 0; kk < 2; ++kk) {
            bf16x8 af[4], bfr[4];
            int kb = kk * 4 + (lane >> 4);
#pragma unroll
            for (int t = 0; t < 4; ++t) {
                int r = mo + t * 16 + (lane & 15);
                af[t] = *(const bf16x8*)&As[r * BK + ((kb ^ (r & 7)) << 3)];
                int n = no + t * 16 + (lane & 15);
                bfr[t] = *(const bf16x8*)&Bs[n * BK + ((kb ^ (n & 7)) << 3)];
            }
#pragma unroll
            for (int i = 0; i < 4; ++i)
#pragma unroll
                for (int j = 0; j < 4; ++j)
                    acc[i][j] = __builtin_amdgcn_mfma_f32_16x16x32_bf16(
                        af[i], bfr[j], acc[i][j], 0, 0, 0);
        }
    }

#pragma unroll
    for (int j = 0; j < 4; ++j) {
        int col = tn + no + j * 16 + (lane & 15);
        float bb = bias[col];
#pragma unroll
        for (int i = 0; i < 4; ++i) {
            int row0 = tm + mo + i * 16 + ((lane >> 4) << 2);
            f32x4 v = acc[i][j];
#pragma unroll
            for (int rr = 0; rr < 4; ++rr)
                H1[(size_t)(row0 + rr) * N + col] = f2bf(fmaxf(v[rr] + bb, 0.f));
        }
    }
}

// GEMM2: A (M x K bf16), B = W2T (N x K bf16). Out = relu(A@B^T + bias) bf16.
__global__ __launch_bounds__(256) void gemm_tn(
    const short* __restrict__ A, const short* __restrict__ Bw,
    const float* __restrict__ bias, unsigned short* __restrict__ Cout,
    int mtiles, int N, int K) {
    constexpr int BK = 64;
    __shared__ __align__(16) short As[128 * BK];
    __shared__ __align__(16) short Bs[128 * BK];
    const int tid = threadIdx.x;
    const int lane = tid & 63;
    const int wave = tid >> 6;
    int mt, nt;
    swizzle_mn(blockIdx.x, mtiles, mt, nt);
    const int tm = mt * 128, tn = nt * 128;
    const int mo = (wave >> 1) * 64;
    const int no = (wave & 1) * 64;

    f32x4 acc[4][4];
#pragma unroll
    for (int i = 0; i < 4; ++i)
#pragma unroll
        for (int j = 0; j < 4; ++j) acc[i][j] = f32x4{0.f, 0.f, 0.f, 0.f};

    const int srow = lane >> 3;
    const int skb = (lane & 7) ^ srow;

    for (int kc = 0; kc < K; kc += BK) {
        __syncthreads();
#pragma unroll
        for (int i = 0; i < 4; ++i) {
            int c = wave * 4 + i;
            int row = c * 8 + srow;
            gl2lds16(A + (size_t)(tm + row) * K + kc + skb * 8, &As[c * 512]);
            gl2lds16(Bw + (size_t)(tn + row) * K + kc + skb * 8, &Bs[c * 512]);
        }
        __syncthreads();
#pragma unroll
        for (int kk = 0; kk < 2; ++kk) {
            bf16x8 af[4], bfr[4];
            int kb = kk * 4 + (lane >> 4);
#pragma unroll
            for (int t = 0; t < 4; ++t) {
                int r = mo + t * 16 + (lane & 15);
                af[t] = *(const bf16x8*)&As[r * BK + ((kb ^ (r & 7)) << 3)];
                int n = no + t * 16 + (lane & 15);
                bfr[t] = *(const bf16x8*)&Bs[n * BK + ((kb ^ (n & 7)) << 3)];
            }
#pragma unroll
            for (int i = 0; i < 4; ++i)
#pragma unroll
                for (int j = 0; j < 4; ++j)
                    acc[i][j] = __builtin_amdgcn_mfma_f32_16x16x32_bf16(
                        af[i], bfr[j], acc[i][j], 0, 0, 0);
        }
    }

#pragma unroll
    for (int j = 0; j < 4; ++j) {
        int col = tn + no + j * 16 + (lane & 15);
        float bb = bias[col];
#pragma unroll
        for (int i = 0; i < 4; ++i) {
            int row0 = tm + mo + i * 16 + ((lane >> 4) << 2);
            f32x4 v = acc[i][j];
#pragma unroll
            for (int rr = 0; rr < 4; ++rr)
                Cout[(size_t)(row0 + rr) * N + col] = f2bf(fmaxf(v[rr] + bb, 0.f));
        }
    }
}

// GEMM3 + finalize. Block = 64 rows x 256 cols (full P row-slab), 4 waves.
// Wave w owns cols 64w..64w+63 with a 4x4 acc (32 MFMA per barrier pair, same
// density as gemm_tn). W3T staged via gl2lds. t-half exchanged via LDS overlay.
__global__ __launch_bounds__(256) void gemm3_final(
    const short* __restrict__ H2, const short* __restrict__ W3T,
    const float* __restrict__ b3, const float* __restrict__ x,
    float* __restrict__ out, float* __restrict__ logdet) {
    constexpr int BK = 64, K = 1024;
    // As 64x64 (8KB) + Bs 256x64 (32KB) = 40KB; Tbuf 64x132 f32 (33.8KB) overlays.
    __shared__ __align__(16) char raw[40960];
    __shared__ float rowsum[64];
    short* As = (short*)raw;
    short* Bs = (short*)(raw + 8192);
    float* Tbuf = (float*)raw;
    const int tid = threadIdx.x;
    const int lane = tid & 63;
    const int wave = tid >> 6;
    const int tm = blockIdx.x * 64;
    const int srow = lane >> 3;
    const int skb = (lane & 7) ^ srow;
    const int l15 = lane & 15;
    const int quad = lane >> 4;

    if (tid < 64) rowsum[tid] = 0.f;

    f32x4 acc[4][4];
#pragma unroll
    for (int i = 0; i < 4; ++i)
#pragma unroll
        for (int j = 0; j < 4; ++j) acc[i][j] = f32x4{0.f, 0.f, 0.f, 0.f};

    for (int kc = 0; kc < K; kc += BK) {
        __syncthreads();
#pragma unroll
        for (int i = 0; i < 10; ++i) {       // 40 chunks: 8 A + 32 B
            int c = wave * 10 + i;
            if (c < 8) {
                int row = c * 8 + srow;
                gl2lds16(H2 + (size_t)(tm + row) * K + kc + skb * 8, &As[c * 512]);
            } else {
                int row = (c - 8) * 8 + srow;
                gl2lds16(W3T + (size_t)row * K + kc + skb * 8, &Bs[(c - 8) * 512]);
            }
        }
        __syncthreads();
#pragma unroll
        for (int kk = 0; kk < 2; ++kk) {
            int kb = kk * 4 + quad;
            bf16x8 af[4], bfr[4];
#pragma unroll
            for (int mt = 0; mt < 4; ++mt) {
                int r = mt * 16 + l15;
                af[mt] = *(const bf16x8*)&As[r * BK + ((kb ^ (r & 7)) << 3)];
            }
#pragma unroll
            for (int nt = 0; nt < 4; ++nt) {
                int n = wave * 64 + nt * 16 + l15;
                bfr[nt] = *(const bf16x8*)&Bs[n * BK + ((kb ^ (n & 7)) << 3)];
            }
#pragma unroll
            for (int mt = 0; mt < 4; ++mt)
#pragma unroll
                for (int nt = 0; nt < 4; ++nt)
                    acc[mt][nt] = __builtin_amdgcn_mfma_f32_16x16x32_bf16(
                        af[mt], bfr[nt], acc[mt][nt], 0, 0, 0);
        }
    }

    // t-waves (cols 128..255) deposit t+bt into Tbuf (overlays staging LDS).
    __syncthreads();
    if (wave >= 2) {
#pragma unroll
        for (int nt = 0; nt < 4; ++nt) {
            int col = wave * 64 + nt * 16 + l15;   // 128..255
            float bb = b3[col];
            int cl = col - 128;
#pragma unroll
            for (int mt = 0; mt < 4; ++mt) {
#pragma unroll
                for (int rr = 0; rr < 4; ++rr) {
                    int m = mt * 16 + quad * 4 + rr;
                    Tbuf[m * 132 + cl] = acc[mt][nt][rr] + bb;
                }
            }
        }
    }
    __syncthreads();
    if (wave < 2) {
#pragma unroll
        for (int mt = 0; mt < 4; ++mt) {
#pragma unroll
            for (int rr = 0; rr < 4; ++rr) {
                int m = mt * 16 + quad * 4 + rr;
                int grow = tm + m;
                float s = 0.f;
#pragma unroll
                for (int nt = 0; nt < 4; ++nt) {
                    int j = wave * 64 + nt * 16 + l15;   // 0..127
                    float p = acc[mt][nt][rr] + b3[j];
                    p = fminf(fmaxf(p, -15.f), 15.f);
                    float e2 = __expf(2.f * p);
                    float ls = (e2 - 1.f) / (e2 + 1.f);  // tanh(p)
                    s += ls;
                    float tt = Tbuf[m * 132 + j];
                    float2 xv = *(const float2*)&x[(size_t)grow * 256 + 2 * j];
                    float2 ov;
                    ov.x = xv.x;
                    ov.y = xv.y * __expf(ls) + tt;
                    *(float2*)&out[(size_t)grow * 256 + 2 * j] = ov;
                }
                s += __shfl_xor(s, 1);
                s += __shfl_xor(s, 2);
                s += __shfl_xor(s, 4);
                s += __shfl_xor(s, 8);
                if (l15 == 0) atomicAdd(&rowsum[m], s);
            }
        }
    }
    __syncthreads();
    if (tid < 64) logdet[tm + tid] = rowsum[tid];
}

extern "C" void kernel_launch(void* const* d_in, const int* in_sizes, int n_in,
                              void* d_out, int out_size, void* d_ws, size_t ws_size,
                              hipStream_t stream) {
    const float* x = (const float*)d_in[0];
    const float* cond = (const float*)d_in[1];
    const float* W1 = (const float*)d_in[2];
    const float* b1 = (const float*)d_in[3];
    const float* W2 = (const float*)d_in[4];
    const float* b2 = (const float*)d_in[5];
    const float* Wsp = (const float*)d_in[6];
    const float* bs = (const float*)d_in[7];
    const float* Wtp = (const float*)d_in[8];
    const float* bt = (const float*)d_in[9];

    char* ws = (char*)d_ws;
    short* W1T = (short*)(ws);                          // 1024x256 bf16 = 512 KB
    short* W2T = (short*)(ws + 524288ull);              // 1024x1024 bf16 = 2 MB
    short* W3T = (short*)(ws + 2621440ull);             // 256x1024 bf16 = 512 KB
    float* b3  = (float*)(ws + 3145728ull);             // 1 KB
    const size_t chunk_base = 3149824ull;

    // Per-chunk scratch: H1 = 2048*R, H2 = 2048*R.
    int n_chunks = 1;
    while (n_chunks < 512) {
        size_t rp = (size_t)B_ROWS / n_chunks;
        if (chunk_base + rp * 4096ull <= ws_size) break;
        n_chunks *= 2;
    }
    const size_t RP = (size_t)B_ROWS / n_chunks;

    float* out = (float*)d_out;
    float* logdet = out + (size_t)B_ROWS * D_DIM;

    transpose_bf16<<<(32768 + 255) / 256, 256, 0, stream>>>(W1, W1T, 256, 1024, 32768);
    transpose_bf16<<<(131072 + 255) / 256, 256, 0, stream>>>(W2, W2T, 1024, 1024, 131072);
    transpose_bf16<<<(16384 + 255) / 256, 256, 0, stream>>>(Wsp, W3T, 1024, 128, 16384);
    transpose_bf16<<<(16384 + 255) / 256, 256, 0, stream>>>(Wtp, W3T + 131072, 1024, 128, 16384);
    prep_b3<<<1, 256, 0, stream>>>(bs, bt, b3);

    for (int c = 0; c < n_chunks; ++c) {
        const size_t r0 = (size_t)c * RP;
        short* H1 = (short*)(ws + chunk_base);
        short* H2 = (short*)(ws + chunk_base + 2048ull * RP);
        const int mtiles = (int)(RP / 128);

        gemm1_fused<<<mtiles * 8, 256, 0, stream>>>(
            x + r0 * D_DIM, cond + r0 * C_DIM, W1T, b1, (unsigned short*)H1, mtiles);
        gemm_tn<<<mtiles * 8, 256, 0, stream>>>(
            H1, W2T, b2, (unsigned short*)H2, mtiles, H_DIM, H_DIM);
        gemm3_final<<<(int)(RP / 64), 256, 0, stream>>>(
            H2, W3T, b3, x + r0 * D_DIM, out + r0 * D_DIM, logdet + r0);
    }
}